// Round 3
// baseline (657.317 us; speedup 1.0000x reference)
//
#include <hip/hip_runtime.h>
#include <cstdint>
#include <cstddef>

#define M_ROWS 65536
#define N_COLS 1024
#define K_DIM  1024

typedef _Float16 f16x8 __attribute__((ext_vector_type(8)));
typedef float f32x4 __attribute__((ext_vector_type(4)));

// ---------------- prep: scale/bias ----------------
__global__ __launch_bounds__(256) void prep_scale_bias(
    const float* __restrict__ gamma, const float* __restrict__ beta,
    const float* __restrict__ mean, const float* __restrict__ var,
    float* __restrict__ bias, float* __restrict__ scale)
{
  int i = blockIdx.x * 256 + threadIdx.x;
  if (i < N_COLS) {
    float s = gamma[i] * rsqrtf(var[i] + 1e-3f);
    scale[i] = s;
    bias[i] = beta[i] - mean[i] * s;
  }
}

// ---------------- prep: W -> Wt (transposed, scaled, f16) ----------------
__global__ __launch_bounds__(256) void prep_wt(
    const float* __restrict__ W, const float* __restrict__ scale,
    _Float16* __restrict__ Wt)
{
  __shared__ float tile[64][68];
  int k0 = blockIdx.x * 64, n0 = blockIdx.y * 64;
  int t = threadIdx.x;
  int kr = t >> 2, q = t & 3;
  #pragma unroll
  for (int j = 0; j < 4; ++j) {
    float4 v = *(const float4*)(W + (size_t)(k0 + kr) * N_COLS + n0 + q * 16 + j * 4);
    *(float4*)(&tile[kr][q * 16 + j * 4]) = v;
  }
  __syncthreads();
  int nr = t >> 2;
  float sn = scale[n0 + nr];
  __align__(16) _Float16 h[16];
  #pragma unroll
  for (int j = 0; j < 16; ++j)
    h[j] = (_Float16)(tile[q * 16 + j][nr] * sn);
  uint4* dst = (uint4*)(Wt + (size_t)(n0 + nr) * K_DIM + k0 + q * 16);
  dst[0] = *(uint4*)(&h[0]);
  dst[1] = *(uint4*)(&h[8]);
}

// ---------------- fused: z = (A @ Wt^T + bias) * priors ; out = sparsemax(z) ----------------
// One block = 32 full rows x 1024 cols. 4 waves, each wave 32x256 (2 m-frags x 16 n-frags).
// A: fp32 global -> reg cvt f16 -> tiny LDS tile (4KB, dbuf, XOR-swizzled).
// B: 2MB L2-resident Wt, loaded directly global->VGPR per fragment.
// Sparsemax on register-resident z: shfl within 16-lane group + LDS combine across 4 waves.
__global__ __launch_bounds__(256, 2) void fused_gemm_sparsemax(
    const float* __restrict__ A, const _Float16* __restrict__ Wt,
    const float* __restrict__ bias, const float* __restrict__ priors,
    float* __restrict__ out)
{
  __shared__ char asmem[16384];          // A tiles: 2 x (32 rows x 64 k x f16) = 2 x 4KB (8KB used)
  __shared__ float red[2][32][4];        // per-row per-wave partials (dbuf)
  __shared__ float redk[2][32][4];       // support-count partials (Newton)

  const int tid = threadIdx.x;
  const int lane = tid & 63, wn = tid >> 6;     // 4 waves = 4 col-bands of 256
  const int li = lane & 15, g = lane >> 4;
  const int m0 = blockIdx.x * 32;

  f32x4 acc[2][16];
  #pragma unroll
  for (int fm = 0; fm < 2; ++fm)
    #pragma unroll
    for (int fn = 0; fn < 16; ++fn) acc[fm][fn] = (f32x4){0.f, 0.f, 0.f, 0.f};

  // ---- A staging helpers (256 threads cover 32x64 fp32 tile: 8 f32/thread) ----
  const int arow = tid >> 3, acol = (tid & 7) * 8;
  const float* aptr = A + (size_t)(m0 + arow) * K_DIM + acol;
  const int awoff = arow * 128 + ((acol * 2) ^ ((arow & 7) << 4));

  float4 a0, a1;
  auto loadA = [&](int kt) {
    a0 = *(const float4*)(aptr + kt * 64);
    a1 = *(const float4*)(aptr + kt * 64 + 4);
  };
  auto storeA = [&](int buf) {
    union { _Float16 h[8]; uint4 u; } p;
    p.h[0] = (_Float16)a0.x; p.h[1] = (_Float16)a0.y;
    p.h[2] = (_Float16)a0.z; p.h[3] = (_Float16)a0.w;
    p.h[4] = (_Float16)a1.x; p.h[5] = (_Float16)a1.y;
    p.h[6] = (_Float16)a1.z; p.h[7] = (_Float16)a1.w;
    *(uint4*)(&asmem[buf * 8192 + awoff]) = p.u;
  };

  // ---- B per-lane base: row (col of z) = wn*256 + fn*16 + li, k-offset g*8 ----
  const _Float16* wb = Wt + (size_t)(wn * 256 + li) * K_DIM + g * 8;
  const int aswz = (li & 7) << 4;

  loadA(0); storeA(0); __syncthreads();

  for (int kt = 0; kt < 16; ++kt) {
    const int cur = kt & 1;
    if (kt < 15) loadA(kt + 1);
    #pragma unroll
    for (int kc = 0; kc < 2; ++kc) {
      const int kb = kt * 64 + kc * 32;
      f16x8 bf[16];
      #pragma unroll
      for (int fn = 0; fn < 16; ++fn)
        bf[fn] = *(const f16x8*)(wb + (size_t)fn * 16 * K_DIM + kb);
      const int koff = (kc * 32 + g * 8) * 2;
      f16x8 af0 = *(const f16x8*)(&asmem[cur * 8192 + li * 128 + (koff ^ aswz)]);
      f16x8 af1 = *(const f16x8*)(&asmem[cur * 8192 + (16 + li) * 128 + (koff ^ aswz)]);
      #pragma unroll
      for (int fn = 0; fn < 16; ++fn) {
        acc[0][fn] = __builtin_amdgcn_mfma_f32_16x16x32_f16(af0, bf[fn], acc[0][fn], 0, 0, 0);
        acc[1][fn] = __builtin_amdgcn_mfma_f32_16x16x32_f16(af1, bf[fn], acc[1][fn], 0, 0, 0);
      }
    }
    if (kt < 15) storeA(cur ^ 1);
    __syncthreads();
  }

  // ---- epilogue: z = (acc + bias) * priors, in registers ----
  float bv[16];
  #pragma unroll
  for (int fn = 0; fn < 16; ++fn) bv[fn] = bias[wn * 256 + fn * 16 + li];

  #pragma unroll
  for (int fm = 0; fm < 2; ++fm)
    #pragma unroll
    for (int r = 0; r < 4; ++r) {
      const float* pp = priors + (size_t)(m0 + fm * 16 + g * 4 + r) * N_COLS + wn * 256 + li;
      #pragma unroll
      for (int fn = 0; fn < 16; ++fn)
        acc[fm][fn][r] = (acc[fm][fn][r] + bv[fn]) * pp[fn * 16];
    }

  // ---- sparsemax: per-lane row chunk = 16 fn-values of row R = fm*16 + g*4 + r ----
  // stage 1: per-row max (wave-partial via shfl over li, combine 4 waves via LDS)
  float mx[2][4];
  #pragma unroll
  for (int fm = 0; fm < 2; ++fm)
    #pragma unroll
    for (int r = 0; r < 4; ++r) {
      float m = acc[fm][0][r];
      #pragma unroll
      for (int fn = 1; fn < 16; ++fn) m = fmaxf(m, acc[fm][fn][r]);
      m = fmaxf(m, __shfl_xor(m, 1, 64));
      m = fmaxf(m, __shfl_xor(m, 2, 64));
      m = fmaxf(m, __shfl_xor(m, 4, 64));
      m = fmaxf(m, __shfl_xor(m, 8, 64));
      mx[fm][r] = m;
    }
  if (li == 0) {
    #pragma unroll
    for (int fm = 0; fm < 2; ++fm)
      #pragma unroll
      for (int r = 0; r < 4; ++r)
        red[0][fm * 16 + g * 4 + r][wn] = mx[fm][r];
  }
  __syncthreads();

  float lo[2][4], hi[2][4];
  #pragma unroll
  for (int fm = 0; fm < 2; ++fm)
    #pragma unroll
    for (int r = 0; r < 4; ++r) {
      float4 q = *(const float4*)(&red[0][fm * 16 + g * 4 + r][0]);
      float M = fmaxf(fmaxf(q.x, q.y), fmaxf(q.z, q.w));
      lo[fm][r] = M - 1.0f;
      hi[fm][r] = M;
    }

  // stage 2: 12 bisections on f(tau) = sum relu(z - tau) - 1 (monotone decreasing)
  float tt[2][4];
  for (int it = 0; it < 12; ++it) {
    const int b = (it + 1) & 1;
    float sv[2][4];
    #pragma unroll
    for (int fm = 0; fm < 2; ++fm)
      #pragma unroll
      for (int r = 0; r < 4; ++r) {
        float t = 0.5f * (lo[fm][r] + hi[fm][r]);
        tt[fm][r] = t;
        float s = 0.f;
        #pragma unroll
        for (int fn = 0; fn < 16; ++fn) s += fmaxf(acc[fm][fn][r] - t, 0.f);
        s += __shfl_xor(s, 1, 64);
        s += __shfl_xor(s, 2, 64);
        s += __shfl_xor(s, 4, 64);
        s += __shfl_xor(s, 8, 64);
        sv[fm][r] = s;
      }
    if (li == 0) {
      #pragma unroll
      for (int fm = 0; fm < 2; ++fm)
        #pragma unroll
        for (int r = 0; r < 4; ++r)
          red[b][fm * 16 + g * 4 + r][wn] = sv[fm][r];
    }
    __syncthreads();
    #pragma unroll
    for (int fm = 0; fm < 2; ++fm)
      #pragma unroll
      for (int r = 0; r < 4; ++r) {
        float4 q = *(const float4*)(&red[b][fm * 16 + g * 4 + r][0]);
        float S = (q.x + q.y) + (q.z + q.w);
        if (S >= 1.f) lo[fm][r] = tt[fm][r]; else hi[fm][r] = tt[fm][r];
      }
  }

  // stage 3: 2 exact Newton polish steps: tau = (sum_{z>tau} z - 1) / k
  float tv[2][4];
  #pragma unroll
  for (int fm = 0; fm < 2; ++fm)
    #pragma unroll
    for (int r = 0; r < 4; ++r) tv[fm][r] = lo[fm][r];

  for (int nit = 0; nit < 2; ++nit) {
    const int b = (13 + nit) & 1;
    float sv[2][4], kv[2][4];
    #pragma unroll
    for (int fm = 0; fm < 2; ++fm)
      #pragma unroll
      for (int r = 0; r < 4; ++r) {
        float s = 0.f, k = 0.f;
        float t = tv[fm][r];
        #pragma unroll
        for (int fn = 0; fn < 16; ++fn) {
          float d = acc[fm][fn][r];
          bool gt = d > t;
          s += gt ? d : 0.f;
          k += gt ? 1.f : 0.f;
        }
        s += __shfl_xor(s, 1, 64); k += __shfl_xor(k, 1, 64);
        s += __shfl_xor(s, 2, 64); k += __shfl_xor(k, 2, 64);
        s += __shfl_xor(s, 4, 64); k += __shfl_xor(k, 4, 64);
        s += __shfl_xor(s, 8, 64); k += __shfl_xor(k, 8, 64);
        sv[fm][r] = s; kv[fm][r] = k;
      }
    if (li == 0) {
      #pragma unroll
      for (int fm = 0; fm < 2; ++fm)
        #pragma unroll
        for (int r = 0; r < 4; ++r) {
          red[b][fm * 16 + g * 4 + r][wn] = sv[fm][r];
          redk[b][fm * 16 + g * 4 + r][wn] = kv[fm][r];
        }
    }
    __syncthreads();
    #pragma unroll
    for (int fm = 0; fm < 2; ++fm)
      #pragma unroll
      for (int r = 0; r < 4; ++r) {
        float4 q = *(const float4*)(&red[b][fm * 16 + g * 4 + r][0]);
        float4 qk = *(const float4*)(&redk[b][fm * 16 + g * 4 + r][0]);
        float S = (q.x + q.y) + (q.z + q.w);
        float K = (qk.x + qk.y) + (qk.z + qk.w);
        tv[fm][r] = (S - 1.f) / K;   // K >= 1 (row max stays in support)
      }
  }

  // ---- write out = relu(z - tau) from f32 registers ----
  #pragma unroll
  for (int fm = 0; fm < 2; ++fm)
    #pragma unroll
    for (int r = 0; r < 4; ++r) {
      float* op = out + (size_t)(m0 + fm * 16 + g * 4 + r) * N_COLS + wn * 256 + li;
      float t = tv[fm][r];
      #pragma unroll
      for (int fn = 0; fn < 16; ++fn)
        op[fn * 16] = fmaxf(acc[fm][fn][r] - t, 0.f);
    }
}

// ---------------- launch ----------------
extern "C" void kernel_launch(void* const* d_in, const int* in_sizes, int n_in,
                              void* d_out, int out_size, void* d_ws, size_t ws_size,
                              hipStream_t stream) {
  const float* inputs = (const float*)d_in[0];
  const float* priors = (const float*)d_in[1];
  const float* W      = (const float*)d_in[2];
  const float* gamma  = (const float*)d_in[3];
  const float* beta   = (const float*)d_in[4];
  const float* mean   = (const float*)d_in[5];
  const float* var    = (const float*)d_in[6];
  float* out = (float*)d_out;

  char* ws = (char*)d_ws;
  float* bias  = (float*)ws;                 // 4 KB
  float* scale = (float*)(ws + 4096);        // 4 KB
  _Float16* Wt = (_Float16*)(ws + 8192);     // 2 MB, [N][K] transposed+scaled

  prep_scale_bias<<<4, 256, 0, stream>>>(gamma, beta, mean, var, bias, scale);
  prep_wt<<<dim3(16, 16), 256, 0, stream>>>(W, scale, Wt);
  fused_gemm_sparsemax<<<M_ROWS / 32, 256, 0, stream>>>(inputs, Wt, bias, priors, out);
}